// Round 10
// baseline (412.123 us; speedup 1.0000x reference)
//
#include <hip/hip_runtime.h>
#include <hip/hip_fp16.h>
#include <stdint.h>

#define BB 512
#define TT 1024
#define II 15
#define HH 64
#define OO 11
#define NC (TT / 64)

typedef __fp16 half2v __attribute__((ext_vector_type(2)));
typedef _Float16 half8 __attribute__((ext_vector_type(8)));
typedef float floatx4 __attribute__((ext_vector_type(4)));
typedef int int4v __attribute__((ext_vector_type(4)));

union PK { int i; half2v h; float f; };
union AU { int4v i; half8 h; };

__device__ __forceinline__ half2v i2h2(int v) { PK u; u.i = v; return u.h; }
__device__ __forceinline__ int h22i(half2v v) { PK u; u.h = v; return u.i; }

__device__ __forceinline__ float FDOT2(half2v a, half2v b, float c) {
    return __builtin_amdgcn_fdot2(a, b, c, false);
}

__device__ __forceinline__ float lane_xor1(float v) {
    PK u; u.f = v;
    // quad_perm(1,0,3,2) = 0xB1 : lane -> lane^1
    u.i = __builtin_amdgcn_mov_dpp(u.i, 0xB1, 0xF, 0xF, false);
    return u.f;
}

__device__ __forceinline__ float lane_xor2(float v) {
    PK u; u.f = v;
    // quad_perm(2,3,0,1) = 0x4E : lane -> lane^2
    u.i = __builtin_amdgcn_mov_dpp(u.i, 0x4E, 0xF, 0xF, false);
    return u.f;
}

// Drain LDS ops, then workgroup barrier (wave-uniform branches; every wave
// executes exactly 1 + NC barriers).
__device__ __forceinline__ void block_sync() {
    asm volatile("s_waitcnt lgkmcnt(0)" ::: "memory");
    __builtin_amdgcn_s_barrier();
}

// v12: TWO recurrence chains per rec wave, latency-shared.
// Evidence R4-R9: every single-chain body = 430-440 cyc/step -> the cost is
// ONE cross-lane round trip (DS queue + crossbar + waits + dep tail), a
// latency floor, insensitive to issue work. So amortize it: one wave runs
// chains A and B interleaved; all 16 bpermutes (8 per chain, register
// crossbar — nothing to sink, unlike R2's LDS-memory prefetches) are issued
// BEFORE a sched_barrier(0), then A's MFMAs+tail, then B's. Both crossbar
// latencies fly together: pair ~ 1 latency + 2 issue-tails ~ 510-550 cyc ->
// ~260 cyc/chain-step vs 437. Geometry: 256 blocks x 128 thr; wave0 = rec
// (both chains; weights/bpidx shared), wave1 = consumer (xs staging + decode
// for both batches, ~8K of its ~28K cyc window). Rec wave still alone on its
// SIMD. MFMA layouts R6/R9-hardware-verified. LDS unchanged (100 KiB).
__global__ __launch_bounds__(128) void rnn_fused(
    const float* __restrict__ x, const float* __restrict__ W_ih,
    const float* __restrict__ b_ih, const float* __restrict__ W_hh,
    const float* __restrict__ b_hh, const float* __restrict__ W_dec,
    const float* __restrict__ b_dec, float* __restrict__ out,
    float* __restrict__ h_last)
{
    __shared__ __align__(16) int xpack[64 * 8];             // 2 KiB
    __shared__ __align__(16) float xsbuf[2][2][64 * 64];    // 64 KiB
    __shared__ __align__(16) _Float16 hring[2][128][HH];    // 32 KiB
    const int tid  = threadIdx.x;
    const int lane = tid & 63;
    const int wid  = tid >> 6;
    const int bA = blockIdx.x * 2;
    const int bB = bA + 1;

    if (wid == 0) {
        // ------------- recurrence producer: chains A,B interleaved -------------
        // W_hh B-fragments (R6/R9-verified): bf[g][s][j] = W_hh[16g+nl][32s+8kq+j]
        const int nl = lane & 15;
        const int kq = lane >> 4;
        half8 bf[4][2];
#pragma unroll
        for (int g = 0; g < 4; ++g)
#pragma unroll
            for (int s = 0; s < 2; ++s)
#pragma unroll
                for (int j = 0; j < 8; ++j)
                    bf[g][s][j] = (_Float16)W_hh[(16 * g + nl) * HH +
                                                 32 * s + 8 * kq + j];

        // bpermute byte-indices (R9-verified): A0 pair 4g+jj lives in lane
        // 8g+2jj (addr = 32g+8jj); A1 pairs +32 lanes (+128 B)
        int bpidx[8];
#pragma unroll
        for (int jj = 0; jj < 4; ++jj) {
            bpidx[jj]     = kq * 32 + 8 * jj;
            bpidx[jj + 4] = bpidx[jj] + 128;
        }
        const bool bsel4 = (lane & 16) != 0;
        const bool bsel5 = (lane & 32) != 0;
        const floatx4 zc = {0.0f, 0.0f, 0.0f, 0.0f};

        block_sync();                            // B0: consumer's xs[0] ready

        float hA = 0.0f, hB = 0.0f;
        int hpkA = 0, hpkB = 0;

        for (int c = 0; c < NC; ++c) {
            const float* xspA = &xsbuf[0][c & 1][0];
            const float* xspB = &xsbuf[1][c & 1][0];
            for (int to = 0; to < 64; to += 8) {
#pragma unroll
                for (int u = 0; u < 8; ++u) {
                    const int ts = to + u;
                    const int t = c * 64 + ts;
                    const float xsvA = xspA[ts * 64 + lane];
                    const float xsvB = xspB[ts * 64 + lane];

                    // ALL 16 bpermutes first: both crossbar latencies in flight
                    int rA[8], rB[8];
#pragma unroll
                    for (int j = 0; j < 8; ++j)
                        rA[j] = __builtin_amdgcn_ds_bpermute(bpidx[j], hpkA);
#pragma unroll
                    for (int j = 0; j < 8; ++j)
                        rB[j] = __builtin_amdgcn_ds_bpermute(bpidx[j], hpkB);
                    __builtin_amdgcn_sched_barrier(0);  // pin: no MFMA above

                    // ---- chain A: MFMAs + tail ----
                    {
                        AU u0; u0.i = (int4v){rA[0], rA[1], rA[2], rA[3]};
                        AU u1; u1.i = (int4v){rA[4], rA[5], rA[6], rA[7]};
                        const half8 a0 = u0.h, a1 = u1.h;
                        floatx4 c0 = __builtin_amdgcn_mfma_f32_16x16x32_f16(a0, bf[0][0], zc, 0, 0, 0);
                        floatx4 d0 = __builtin_amdgcn_mfma_f32_16x16x32_f16(a1, bf[0][1], zc, 0, 0, 0);
                        floatx4 c1 = __builtin_amdgcn_mfma_f32_16x16x32_f16(a0, bf[1][0], zc, 0, 0, 0);
                        floatx4 d1 = __builtin_amdgcn_mfma_f32_16x16x32_f16(a1, bf[1][1], zc, 0, 0, 0);
                        floatx4 c2 = __builtin_amdgcn_mfma_f32_16x16x32_f16(a0, bf[2][0], zc, 0, 0, 0);
                        floatx4 d2 = __builtin_amdgcn_mfma_f32_16x16x32_f16(a1, bf[2][1], zc, 0, 0, 0);
                        floatx4 c3 = __builtin_amdgcn_mfma_f32_16x16x32_f16(a0, bf[3][0], zc, 0, 0, 0);
                        floatx4 d3 = __builtin_amdgcn_mfma_f32_16x16x32_f16(a1, bf[3][1], zc, 0, 0, 0);
                        const float v0 = c0[0] + d0[0];
                        const float v1 = c1[0] + d1[0];
                        const float v2 = c2[0] + d2[0];
                        const float v3 = c3[0] + d3[0];
                        const float r01 = bsel4 ? v1 : v0;
                        const float r23 = bsel4 ? v3 : v2;
                        hA = fmaxf((bsel5 ? r23 : r01) + xsvA, 0.0f);
                        hring[0][t & 127][lane] = (_Float16)hA;
                        hpkA = h22i(__builtin_amdgcn_cvt_pkrtz(hA, lane_xor1(hA)));
                    }
                    // ---- chain B: MFMAs + tail ----
                    {
                        AU u0; u0.i = (int4v){rB[0], rB[1], rB[2], rB[3]};
                        AU u1; u1.i = (int4v){rB[4], rB[5], rB[6], rB[7]};
                        const half8 a0 = u0.h, a1 = u1.h;
                        floatx4 c0 = __builtin_amdgcn_mfma_f32_16x16x32_f16(a0, bf[0][0], zc, 0, 0, 0);
                        floatx4 d0 = __builtin_amdgcn_mfma_f32_16x16x32_f16(a1, bf[0][1], zc, 0, 0, 0);
                        floatx4 c1 = __builtin_amdgcn_mfma_f32_16x16x32_f16(a0, bf[1][0], zc, 0, 0, 0);
                        floatx4 d1 = __builtin_amdgcn_mfma_f32_16x16x32_f16(a1, bf[1][1], zc, 0, 0, 0);
                        floatx4 c2 = __builtin_amdgcn_mfma_f32_16x16x32_f16(a0, bf[2][0], zc, 0, 0, 0);
                        floatx4 d2 = __builtin_amdgcn_mfma_f32_16x16x32_f16(a1, bf[2][1], zc, 0, 0, 0);
                        floatx4 c3 = __builtin_amdgcn_mfma_f32_16x16x32_f16(a0, bf[3][0], zc, 0, 0, 0);
                        floatx4 d3 = __builtin_amdgcn_mfma_f32_16x16x32_f16(a1, bf[3][1], zc, 0, 0, 0);
                        const float v0 = c0[0] + d0[0];
                        const float v1 = c1[0] + d1[0];
                        const float v2 = c2[0] + d2[0];
                        const float v3 = c3[0] + d3[0];
                        const float r01 = bsel4 ? v1 : v0;
                        const float r23 = bsel4 ? v3 : v2;
                        hB = fmaxf((bsel5 ? r23 : r01) + xsvB, 0.0f);
                        hring[1][t & 127][lane] = (_Float16)hB;
                        hpkB = h22i(__builtin_amdgcn_cvt_pkrtz(hB, lane_xor1(hB)));
                    }
                }
            }
            block_sync();                      // chunk c h ready; xs[c+1] ready
        }
        h_last[bA * HH + lane] = hA;
        h_last[bB * HH + lane] = hB;
    } else {
        // ---- consumer: xproj producer (1 ahead) + decoder (1 behind), both chains ----
        half2v wx[8];
#pragma unroll
        for (int j = 0; j < 7; ++j)
            wx[j] = __builtin_amdgcn_cvt_pkrtz(W_ih[lane * II + 2 * j],
                                               W_ih[lane * II + 2 * j + 1]);
        wx[7] = __builtin_amdgcn_cvt_pkrtz(W_ih[lane * II + 14],
                                           b_ih[lane] + b_hh[lane]);

        const int od = lane >> 2;
        const int oc = (od < OO) ? od : 0;
        const int ks = lane & 3;
        half2v wdec[8];
#pragma unroll
        for (int p = 0; p < 8; ++p)
            wdec[p] = __builtin_amdgcn_cvt_pkrtz(
                W_dec[oc * HH + (ks * 8 + p) * 2],
                W_dec[oc * HH + (ks * 8 + p) * 2 + 1]);
        const float bd = b_dec[oc];
        const bool dostore = (ks == 0) && (od < OO);

        const float* xbc[2] = { x + (size_t)bA * TT * II,
                                x + (size_t)bB * TT * II };
        float* outc[2] = { out + (size_t)bA * TT * OO + od,
                           out + (size_t)bB * TT * OO + od };

        auto stage_xs = [&](int ch, int chunk) __attribute__((always_inline)) {
            const float* xc = xbc[ch] + (size_t)(chunk * 64 + lane) * II;
            float cf[II];
#pragma unroll
            for (int i = 0; i < II; ++i) cf[i] = xc[i];
            int4v p0, p1;
            p0.x = h22i(__builtin_amdgcn_cvt_pkrtz(cf[0], cf[1]));
            p0.y = h22i(__builtin_amdgcn_cvt_pkrtz(cf[2], cf[3]));
            p0.z = h22i(__builtin_amdgcn_cvt_pkrtz(cf[4], cf[5]));
            p0.w = h22i(__builtin_amdgcn_cvt_pkrtz(cf[6], cf[7]));
            p1.x = h22i(__builtin_amdgcn_cvt_pkrtz(cf[8], cf[9]));
            p1.y = h22i(__builtin_amdgcn_cvt_pkrtz(cf[10], cf[11]));
            p1.z = h22i(__builtin_amdgcn_cvt_pkrtz(cf[12], cf[13]));
            p1.w = h22i(__builtin_amdgcn_cvt_pkrtz(cf[14], 1.0f));
            *(int4v*)&xpack[lane * 8] = p0;
            *(int4v*)&xpack[lane * 8 + 4] = p1;

            const int4v* xp4 = (const int4v*)&xpack[0];
            float* xsd = &xsbuf[ch][chunk & 1][0];
#pragma unroll 4
            for (int ts = 0; ts < 64; ++ts) {
                const int4v xv0 = xp4[2 * ts];      // uniform-addr broadcast
                const int4v xv1 = xp4[2 * ts + 1];
                float t0 = FDOT2(i2h2(xv0.x), wx[0], 0.0f);
                float t1 = FDOT2(i2h2(xv0.y), wx[1], 0.0f);
                float t2 = FDOT2(i2h2(xv0.z), wx[2], 0.0f);
                float t3 = FDOT2(i2h2(xv0.w), wx[3], 0.0f);
                float t4 = FDOT2(i2h2(xv1.x), wx[4], 0.0f);
                float t5 = FDOT2(i2h2(xv1.y), wx[5], 0.0f);
                float t6 = FDOT2(i2h2(xv1.z), wx[6], 0.0f);
                float t7 = FDOT2(i2h2(xv1.w), wx[7], 0.0f);
                xsd[ts * 64 + lane] = ((t0 + t1) + (t2 + t3)) +
                                      ((t4 + t5) + (t6 + t7));
            }
        };

        auto decode_chunk = [&](int ch, int c) __attribute__((always_inline)) {
#pragma unroll 4
            for (int lt = 0; lt < 64; ++lt) {
                const int t = c * 64 + lt;
                const char* row = (const char*)&hring[ch][t & 127][0];
                const int4v d0 = *(const int4v*)(row + ks * 32);
                const int4v d1 = *(const int4v*)(row + ks * 32 + 16);
                float dacc = FDOT2(i2h2(d0.x), wdec[0], 0.0f);
                dacc = FDOT2(i2h2(d0.y), wdec[1], dacc);
                dacc = FDOT2(i2h2(d0.z), wdec[2], dacc);
                dacc = FDOT2(i2h2(d0.w), wdec[3], dacc);
                dacc = FDOT2(i2h2(d1.x), wdec[4], dacc);
                dacc = FDOT2(i2h2(d1.y), wdec[5], dacc);
                dacc = FDOT2(i2h2(d1.z), wdec[6], dacc);
                dacc = FDOT2(i2h2(d1.w), wdec[7], dacc);
                dacc += lane_xor1(dacc);       // quad reduce over ks
                dacc += lane_xor2(dacc);
                if (dostore)
                    outc[ch][(size_t)t * OO] = fmaxf(dacc + bd, 0.0f);
            }
        };

        stage_xs(0, 0);
        stage_xs(1, 0);
        block_sync();                          // B0

        for (int c = 0; c < NC; ++c) {
            if (c + 1 < NC) { stage_xs(0, c + 1); stage_xs(1, c + 1); }
            if (c >= 1)     { decode_chunk(0, c - 1); decode_chunk(1, c - 1); }
            block_sync();
        }
        decode_chunk(0, NC - 1);
        decode_chunk(1, NC - 1);
    }
}

extern "C" void kernel_launch(void* const* d_in, const int* in_sizes, int n_in,
                              void* d_out, int out_size, void* d_ws, size_t ws_size,
                              hipStream_t stream) {
    const float* x     = (const float*)d_in[0];
    const float* W_ih  = (const float*)d_in[1];
    const float* b_ih  = (const float*)d_in[2];
    const float* W_hh  = (const float*)d_in[3];
    const float* b_hh  = (const float*)d_in[4];
    const float* W_dec = (const float*)d_in[5];
    const float* b_dec = (const float*)d_in[6];

    float* out    = (float*)d_out;
    float* h_last = out + (size_t)BB * TT * OO;   // second tuple output

    rnn_fused<<<BB / 2, 128, 0, stream>>>(x, W_ih, b_ih, W_hh, b_hh,
                                          W_dec, b_dec, out, h_last);
}

// Round 11
// 247.080 us; speedup vs baseline: 1.6680x; 1.6680x over previous
//
#include <hip/hip_runtime.h>
#include <hip/hip_fp16.h>
#include <stdint.h>

#define BB 512
#define TT 1024
#define II 15
#define HH 64
#define OO 11
#define NC (TT / 64)

typedef __fp16 half2v __attribute__((ext_vector_type(2)));
typedef float floatx4 __attribute__((ext_vector_type(4)));
typedef int int4v __attribute__((ext_vector_type(4)));

union PK { int i; half2v h; float f; };

__device__ __forceinline__ half2v i2h2(int v) { PK u; u.i = v; return u.h; }
__device__ __forceinline__ int h22i(half2v v) { PK u; u.h = v; return u.i; }

__device__ __forceinline__ float FDOT2(half2v a, half2v b, float c) {
    return __builtin_amdgcn_fdot2(a, b, c, false);
}

__device__ __forceinline__ float lane_xor1(float v) {
    PK u; u.f = v;
    // quad_perm(1,0,3,2) = 0xB1 : lane -> lane^1
    u.i = __builtin_amdgcn_mov_dpp(u.i, 0xB1, 0xF, 0xF, false);
    return u.f;
}

__device__ __forceinline__ float lane_xor2(float v) {
    PK u; u.f = v;
    // quad_perm(2,3,0,1) = 0x4E : lane -> lane^2
    u.i = __builtin_amdgcn_mov_dpp(u.i, 0x4E, 0xF, 0xF, false);
    return u.f;
}

// Drain LDS ops, then workgroup barrier (wave-uniform branches; every wave
// executes exactly 1 + NC barriers).
__device__ __forceinline__ void block_sync() {
    asm volatile("s_waitcnt lgkmcnt(0)" ::: "memory");
    __builtin_amdgcn_s_barrier();
}

// v13 = RESTORE of the measured-best kernel (R8, 182.6us kernel / ~248us
// total). Final model, consistent with all 11 experiments:
//   step T ~= RAW write->read LDS round trip (~250cy at 1 wave) +
//             irreducible dependent tail (~100cy) + fixed (~80cy) ~= 430cy.
// Invariant across LDS-dot / readlane / MFMA / bpermute bodies (428-467).
// bpermutes serialize ~47cy each in the single-wave DS queue (R9:8->437,
// R10:16->814); uniform ds_reads pipeline (R7~R8). Chain-batching in one
// wave regresses (R2, R10); same-SIMD co-residency regresses (R3); on-chain
// additions cost full price (R4, R6); off-chain offloads win (R5, R7).
// Structure: 256 blocks x 4 waves (1 block/CU). Waves 0,1: pure recurrence
// for batch 2*blk+w, alone on their SIMDs, 16 readlane-pairs (hidden in the
// RAW window) + 4 uniform b128 LDS pairs, publishing h(t) to a 128-slot LDS
// ring. Waves 2,3: consumers — xproj (one chunk ahead, into a double-buffered
// xs plane) + decoder (one chunk behind, straight to out). One barrier per
// 64-step chunk. 1024 x 430cy / 2.4GHz ~= 183us kernel; ~66us fixed harness
// overhead. Latency floor — not a BW/compute roofline (HBM 2.7%, VALU 52%).
__global__ __launch_bounds__(256) void rnn_fused(
    const float* __restrict__ x, const float* __restrict__ W_ih,
    const float* __restrict__ b_ih, const float* __restrict__ W_hh,
    const float* __restrict__ b_hh, const float* __restrict__ W_dec,
    const float* __restrict__ b_dec, float* __restrict__ out,
    float* __restrict__ h_last)
{
    __shared__ __align__(16) int xpack[2][64 * 8];          // 4 KiB
    __shared__ __align__(16) float xsbuf[2][2][64 * 64];    // 64 KiB
    __shared__ __align__(16) _Float16 hring[2][128][HH];    // 32 KiB
    const int tid  = threadIdx.x;
    const int lane = tid & 63;
    const int wid  = tid >> 6;
    const int w = wid & 1;
    const int b = blockIdx.x * 2 + w;
    const float* xb = x + (size_t)b * TT * II;

    if (wid < 2) {
        // ---------------- recurrence producer (pure) ----------------
        // recurrent weights: whh[p] = (W_hh[lane][2p], W_hh[lane][2p+1])
        half2v whh[32];
#pragma unroll
        for (int p = 0; p < 32; ++p)
            whh[p] = __builtin_amdgcn_cvt_pkrtz(W_hh[lane * HH + 2 * p],
                                                W_hh[lane * HH + 2 * p + 1]);

        hring[w][127][lane] = (_Float16)0.0f;    // h(-1) = 0 lives in slot 127

        block_sync();                            // B0: consumers' xs[0] ready

        float h = 0.0f;
        int hpk = 0;   // packed (h[lane&~1], h[lane|1]) from prev step (h=0)

        for (int c = 0; c < NC; ++c) {
            const float* xsp = &xsbuf[w][c & 1][0];
            for (int to = 0; to < 64; to += 8) {
#pragma unroll
                for (int u = 0; u < 8; ++u) {
                    const int ts = to + u;
                    const int t = c * 64 + ts;

                    // LDS broadcast reads of h(t-1)[32..63]: 4 uniform b128
                    const int4v* hb4 =
                        (const int4v*)&hring[w][(t + 127) & 127][0];
                    int4v hb[4];
#pragma unroll
                    for (int q = 0; q < 4; ++q) hb[q] = hb4[q + 4];
                    const float xsv = xsp[ts * 64 + lane];

                    // register-broadcast path: h(t-1)[0..31] pairs live in
                    // even lanes' hpk; 16 readlane+dot fill the RAW window
                    float a0, a1, a2, a3, a4, a5, a6, a7;
                    a0 = FDOT2(i2h2(__builtin_amdgcn_readlane(hpk, 0)),  whh[0], 0.0f);
                    a1 = FDOT2(i2h2(__builtin_amdgcn_readlane(hpk, 2)),  whh[1], 0.0f);
                    a2 = FDOT2(i2h2(__builtin_amdgcn_readlane(hpk, 4)),  whh[2], 0.0f);
                    a3 = FDOT2(i2h2(__builtin_amdgcn_readlane(hpk, 6)),  whh[3], 0.0f);
                    a4 = FDOT2(i2h2(__builtin_amdgcn_readlane(hpk, 8)),  whh[4], 0.0f);
                    a5 = FDOT2(i2h2(__builtin_amdgcn_readlane(hpk, 10)), whh[5], 0.0f);
                    a6 = FDOT2(i2h2(__builtin_amdgcn_readlane(hpk, 12)), whh[6], 0.0f);
                    a7 = FDOT2(i2h2(__builtin_amdgcn_readlane(hpk, 14)), whh[7], 0.0f);
                    a0 = FDOT2(i2h2(__builtin_amdgcn_readlane(hpk, 16)), whh[8],  a0);
                    a1 = FDOT2(i2h2(__builtin_amdgcn_readlane(hpk, 18)), whh[9],  a1);
                    a2 = FDOT2(i2h2(__builtin_amdgcn_readlane(hpk, 20)), whh[10], a2);
                    a3 = FDOT2(i2h2(__builtin_amdgcn_readlane(hpk, 22)), whh[11], a3);
                    a4 = FDOT2(i2h2(__builtin_amdgcn_readlane(hpk, 24)), whh[12], a4);
                    a5 = FDOT2(i2h2(__builtin_amdgcn_readlane(hpk, 26)), whh[13], a5);
                    a6 = FDOT2(i2h2(__builtin_amdgcn_readlane(hpk, 28)), whh[14], a6);
                    a7 = FDOT2(i2h2(__builtin_amdgcn_readlane(hpk, 30)), whh[15], a7);

                    // LDS dots: round q consumes hb[q] (pairs 16+4q .. 19+4q)
#pragma unroll
                    for (int q = 0; q < 4; ++q) {
                        const int base = 16 + 4 * q;
                        if ((q & 1) == 0) {
                            a0 = FDOT2(i2h2(hb[q].x), whh[base + 0], a0);
                            a1 = FDOT2(i2h2(hb[q].y), whh[base + 1], a1);
                            a2 = FDOT2(i2h2(hb[q].z), whh[base + 2], a2);
                            a3 = FDOT2(i2h2(hb[q].w), whh[base + 3], a3);
                        } else {
                            a4 = FDOT2(i2h2(hb[q].x), whh[base + 0], a4);
                            a5 = FDOT2(i2h2(hb[q].y), whh[base + 1], a5);
                            a6 = FDOT2(i2h2(hb[q].z), whh[base + 2], a6);
                            a7 = FDOT2(i2h2(hb[q].w), whh[base + 3], a7);
                        }
                    }
                    const float s = ((a0 + a1) + (a2 + a3)) +
                                    ((a4 + a5) + (a6 + a7));
                    h = fmaxf(s + xsv, 0.0f);
                    hring[w][t & 127][lane] = (_Float16)h;   // publish h(t)

                    // pack pair for next step's readlane path (off the DS pipe)
                    hpk = h22i(__builtin_amdgcn_cvt_pkrtz(h, lane_xor1(h)));
                }
            }
            block_sync();                      // chunk c h ready; xs[c+1] ready
        }
        h_last[b * HH + lane] = h;
    } else {
        // -------- consumer: xproj producer (1 chunk ahead) + decoder (1 behind) --------
        // xproj weights, lane = n: pair 7 = (w14, bias) matching x pair (x14, 1.0)
        half2v wx[8];
#pragma unroll
        for (int j = 0; j < 7; ++j)
            wx[j] = __builtin_amdgcn_cvt_pkrtz(W_ih[lane * II + 2 * j],
                                               W_ih[lane * II + 2 * j + 1]);
        wx[7] = __builtin_amdgcn_cvt_pkrtz(W_ih[lane * II + 14],
                                           b_ih[lane] + b_hh[lane]);

        // decode lane role: o = lane>>2 (output col, valid < 11), ks = lane&3
        const int od = lane >> 2;
        const int oc = (od < OO) ? od : 0;     // clamp for safe weight loads
        const int ks = lane & 3;
        half2v wdec[8];
#pragma unroll
        for (int p = 0; p < 8; ++p)
            wdec[p] = __builtin_amdgcn_cvt_pkrtz(
                W_dec[oc * HH + (ks * 8 + p) * 2],
                W_dec[oc * HH + (ks * 8 + p) * 2 + 1]);
        const float bd = b_dec[oc];
        const bool dostore = (ks == 0) && (od < OO);
        float* outb = out + (size_t)b * TT * OO + od;

        // stage x chunk + compute xs plane for that chunk (lane = ts for
        // staging, lane = n for the dot loop; in-wave LDS RAW is in-order)
        auto stage_xs = [&](int chunk) __attribute__((always_inline)) {
            const float* xc = xb + (size_t)(chunk * 64 + lane) * II;
            float cf[II];
#pragma unroll
            for (int i = 0; i < II; ++i) cf[i] = xc[i];
            int4v p0, p1;
            p0.x = h22i(__builtin_amdgcn_cvt_pkrtz(cf[0], cf[1]));
            p0.y = h22i(__builtin_amdgcn_cvt_pkrtz(cf[2], cf[3]));
            p0.z = h22i(__builtin_amdgcn_cvt_pkrtz(cf[4], cf[5]));
            p0.w = h22i(__builtin_amdgcn_cvt_pkrtz(cf[6], cf[7]));
            p1.x = h22i(__builtin_amdgcn_cvt_pkrtz(cf[8], cf[9]));
            p1.y = h22i(__builtin_amdgcn_cvt_pkrtz(cf[10], cf[11]));
            p1.z = h22i(__builtin_amdgcn_cvt_pkrtz(cf[12], cf[13]));
            p1.w = h22i(__builtin_amdgcn_cvt_pkrtz(cf[14], 1.0f));
            *(int4v*)&xpack[w][lane * 8] = p0;
            *(int4v*)&xpack[w][lane * 8 + 4] = p1;

            const int4v* xp4 = (const int4v*)&xpack[w][0];
            float* xsd = &xsbuf[w][chunk & 1][0];
#pragma unroll 4
            for (int ts = 0; ts < 64; ++ts) {
                const int4v xv0 = xp4[2 * ts];      // uniform-addr broadcast
                const int4v xv1 = xp4[2 * ts + 1];
                float t0 = FDOT2(i2h2(xv0.x), wx[0], 0.0f);
                float t1 = FDOT2(i2h2(xv0.y), wx[1], 0.0f);
                float t2 = FDOT2(i2h2(xv0.z), wx[2], 0.0f);
                float t3 = FDOT2(i2h2(xv0.w), wx[3], 0.0f);
                float t4 = FDOT2(i2h2(xv1.x), wx[4], 0.0f);
                float t5 = FDOT2(i2h2(xv1.y), wx[5], 0.0f);
                float t6 = FDOT2(i2h2(xv1.z), wx[6], 0.0f);
                float t7 = FDOT2(i2h2(xv1.w), wx[7], 0.0f);
                xsd[ts * 64 + lane] = ((t0 + t1) + (t2 + t3)) +
                                      ((t4 + t5) + (t6 + t7));
            }
        };

        auto decode_chunk = [&](int c) __attribute__((always_inline)) {
#pragma unroll 4
            for (int lt = 0; lt < 64; ++lt) {
                const int t = c * 64 + lt;
                const char* row = (const char*)&hring[w][t & 127][0];
                const int4v d0 = *(const int4v*)(row + ks * 32);
                const int4v d1 = *(const int4v*)(row + ks * 32 + 16);
                float dacc = FDOT2(i2h2(d0.x), wdec[0], 0.0f);
                dacc = FDOT2(i2h2(d0.y), wdec[1], dacc);
                dacc = FDOT2(i2h2(d0.z), wdec[2], dacc);
                dacc = FDOT2(i2h2(d0.w), wdec[3], dacc);
                dacc = FDOT2(i2h2(d1.x), wdec[4], dacc);
                dacc = FDOT2(i2h2(d1.y), wdec[5], dacc);
                dacc = FDOT2(i2h2(d1.z), wdec[6], dacc);
                dacc = FDOT2(i2h2(d1.w), wdec[7], dacc);
                dacc += lane_xor1(dacc);       // quad reduce over ks
                dacc += lane_xor2(dacc);
                if (dostore)
                    outb[(size_t)t * OO] = fmaxf(dacc + bd, 0.0f);
            }
        };

        stage_xs(0);
        block_sync();                          // B0

        for (int c = 0; c < NC; ++c) {
            if (c + 1 < NC) stage_xs(c + 1);   // fill xsbuf[(c+1)&1]
            if (c >= 1) decode_chunk(c - 1);   // rec writes the other half
            block_sync();
        }
        decode_chunk(NC - 1);                  // after final barrier; no more syncs
    }
}

extern "C" void kernel_launch(void* const* d_in, const int* in_sizes, int n_in,
                              void* d_out, int out_size, void* d_ws, size_t ws_size,
                              hipStream_t stream) {
    const float* x     = (const float*)d_in[0];
    const float* W_ih  = (const float*)d_in[1];
    const float* b_ih  = (const float*)d_in[2];
    const float* W_hh  = (const float*)d_in[3];
    const float* b_hh  = (const float*)d_in[4];
    const float* W_dec = (const float*)d_in[5];
    const float* b_dec = (const float*)d_in[6];

    float* out    = (float*)d_out;
    float* h_last = out + (size_t)BB * TT * OO;   // second tuple output

    rnn_fused<<<BB / 2, 256, 0, stream>>>(x, W_ih, b_ih, W_hh, b_hh,
                                          W_dec, b_dec, out, h_last);
}